// Round 2
// baseline (972.180 us; speedup 1.0000x reference)
//
// Round 2: fix probable d_ws overflow — ws_size-adaptive layout, bf16 intermediates,
// chunked QKV/attn and FFN. Compute structure unchanged from round 1 (m97 GEMM).
#include <hip/hip_runtime.h>
#include <stdint.h>

#define BATCH 256
#define SEQ   80
#define DIM   1024
#define HEADS 8
#define HDIM  128
#define HID   4096
#define NTOK  (BATCH * SEQ)   // 20480

typedef unsigned short u16;
using short8_t = __attribute__((ext_vector_type(8))) short;   // 8 bf16 (4 VGPRs)
using f32x4    = __attribute__((ext_vector_type(4))) float;   // MFMA accumulator

__device__ __forceinline__ u16 f2bf(float f) {
  unsigned u = __float_as_uint(f);
  u += 0x7fffu + ((u >> 16) & 1u);   // RNE; inputs are finite
  return (u16)(u >> 16);
}
__device__ __forceinline__ float bf2f(u16 u) {
  return __uint_as_float(((unsigned)u) << 16);
}

__device__ __forceinline__ float gelu_exact(float v) {
  return 0.5f * v * (1.0f + erff(v * 0.70710678118654752f));
}

// async global->LDS, 16B per lane; lds dest = base + lane*16 (base wave-uniform)
#define GLD16(gp, lp)                                                   \
  __builtin_amdgcn_global_load_lds(                                     \
      (__attribute__((address_space(1))) void*)(void*)(gp),             \
      (__attribute__((address_space(3))) void*)(void*)(lp), 16, 0, 0)

// ---------------------------------------------------------------- casts
__global__ __launch_bounds__(256) void cast_bf16_kernel(
    const float* __restrict__ in, u16* __restrict__ out, int n4) {
  int i = blockIdx.x * 256 + threadIdx.x;
  int stride = gridDim.x * 256;
  for (; i < n4; i += stride) {
    float4 v = ((const float4*)in)[i];
    uint2 o;
    o.x = (unsigned)f2bf(v.x) | ((unsigned)f2bf(v.y) << 16);
    o.y = (unsigned)f2bf(v.z) | ((unsigned)f2bf(v.w) << 16);
    ((uint2*)out)[i] = o;
  }
}

// in: R x C fp32 row-major -> out: C x R bf16 row-major  (R,C multiples of 32)
__global__ __launch_bounds__(256) void transpose_cast_kernel(
    const float* __restrict__ in, u16* __restrict__ out, int R, int C) {
  __shared__ float tile[32][33];
  int c0 = blockIdx.x * 32, r0 = blockIdx.y * 32;
  for (int k = 0; k < 4; k++) {
    int i = threadIdx.y + k * 8;
    tile[i][threadIdx.x] = in[(size_t)(r0 + i) * C + c0 + threadIdx.x];
  }
  __syncthreads();
  for (int k = 0; k < 4; k++) {
    int i = threadIdx.y + k * 8;
    out[(size_t)(c0 + i) * R + r0 + threadIdx.x] = f2bf(tile[threadIdx.x][i]);
  }
}

// ---------------------------------------------------------------- GEMM (m97 structure)
// C[M,N] = A[M,K] * Bt[N,K]^T, bf16 out.  128x128 tile, BK=64, 4 waves (2x2), 16x16x32.
// EPI: 0 = plain; 1 = +bias then exact GELU; 2 = +bias.
template <int EPI>
__global__ __launch_bounds__(256) void gemm_bt(
    const u16* __restrict__ A, const u16* __restrict__ Bt,
    const float* __restrict__ bias, u16* __restrict__ outp,
    int M, int N, int K) {
  __shared__ __align__(16) u16 As[128 * 64];
  __shared__ __align__(16) u16 Bs[128 * 64];
  const int t = threadIdx.x, lane = t & 63, wave = t >> 6;
  const int wm = wave >> 1, wn = wave & 1;
  const int lo = lane & 15, hi = lane >> 4;
  const size_t arow0 = (size_t)blockIdx.y * 128;
  const size_t brow0 = (size_t)blockIdx.x * 128;

  f32x4 acc[4][4] = {};

  for (int k0 = 0; k0 < K; k0 += 64) {
#pragma unroll
    for (int i = 0; i < 4; i++) {
      int flat = i * 256 + t;
      int row = flat >> 3;
      int col = (flat & 7) * 8;
      GLD16(A + (arow0 + row) * K + k0 + col, &As[(i * 256 + wave * 64) * 8]);
      GLD16(Bt + (brow0 + row) * K + k0 + col, &Bs[(i * 256 + wave * 64) * 8]);
    }
    asm volatile("s_waitcnt vmcnt(0)" ::: "memory");
    __syncthreads();
#pragma unroll
    for (int kk = 0; kk < 2; kk++) {
      short8_t af[4], bf[4];
#pragma unroll
      for (int m = 0; m < 4; m++)
        af[m] = *(const short8_t*)&As[(wm * 64 + m * 16 + lo) * 64 + kk * 32 + hi * 8];
#pragma unroll
      for (int n = 0; n < 4; n++)
        bf[n] = *(const short8_t*)&Bs[(wn * 64 + n * 16 + lo) * 64 + kk * 32 + hi * 8];
#pragma unroll
      for (int m = 0; m < 4; m++)
#pragma unroll
        for (int n = 0; n < 4; n++)
          acc[m][n] = __builtin_amdgcn_mfma_f32_16x16x32_bf16(af[m], bf[n], acc[m][n], 0, 0, 0);
    }
    __syncthreads();
  }

  const size_t orow0 = (size_t)blockIdx.y * 128 + wm * 64;
  const int ocol0 = blockIdx.x * 128 + wn * 64;
#pragma unroll
  for (int n = 0; n < 4; n++) {
    int col = ocol0 + n * 16 + lo;
    float bv = 0.f;
    if constexpr (EPI != 0) bv = bias[col];
#pragma unroll
    for (int m = 0; m < 4; m++) {
#pragma unroll
      for (int j = 0; j < 4; j++) {
        size_t row = orow0 + m * 16 + hi * 4 + j;
        float v = acc[m][n][j] + bv;
        if constexpr (EPI == 1) v = gelu_exact(v);
        outp[row * N + col] = f2bf(v);
      }
    }
  }
}

// ---------------------------------------------------------------- attention
// One wave per (local b, h). QKV chunk: [nb*80][3072] bf16 (Q|K|V, head h at h*128).
// S^T = K*Q^T (both operands contiguous-K); softmax over keys via shfl_xor(16/32);
// post-softmax relative bias; P staged to LDS (keys padded to 96); out = P*V (bf16).
__global__ __launch_bounds__(64) void attn_kernel(
    const u16* __restrict__ QKV, const float* __restrict__ bias_table,
    u16* __restrict__ attnout) {
  __shared__ __align__(16) u16 Kt[80 * 128];   // [key][d]; reused as P [80][104]
  __shared__ __align__(16) u16 Vt[96 * 128];   // [key][d], rows 80..95 zeroed
  __shared__ float bias_l[159];

  const int bh = blockIdx.x;
  const int b = bh >> 3, h = bh & 7;           // b = local batch index in chunk
  const int lane = threadIdx.x, lo = lane & 15, hi = lane >> 4;
  const size_t tokbase = (size_t)b * SEQ * 3072;
  const u16* Qg = QKV + tokbase + h * HDIM;
  const u16* Kg = QKV + tokbase + 1024 + h * HDIM;
  const u16* Vg = QKV + tokbase + 2048 + h * HDIM;

#pragma unroll
  for (int i = 0; i < 20; i++) {
    int flat = i * 64 + lane;
    int row = flat >> 4;
    int col = (flat & 15) * 8;
    GLD16(Kg + (size_t)row * 3072 + col, &Kt[i * 512]);
    GLD16(Vg + (size_t)row * 3072 + col, &Vt[i * 512]);
  }
  for (int i = lane; i < 16 * 128; i += 64) Vt[80 * 128 + i] = 0;  // V pad rows
  for (int i = lane; i < 159; i += 64) bias_l[i] = bias_table[i * 8 + h];
  asm volatile("s_waitcnt vmcnt(0)" ::: "memory");
  __syncthreads();

  // ---- S^T[key][q] = K * Q^T
  f32x4 sa[5][5] = {};
#pragma unroll
  for (int ks = 0; ks < 4; ks++) {
    short8_t ak[5], bq[5];
#pragma unroll
    for (int m = 0; m < 5; m++)
      ak[m] = *(const short8_t*)&Kt[(m * 16 + lo) * 128 + ks * 32 + hi * 8];
#pragma unroll
    for (int n = 0; n < 5; n++)
      bq[n] = *(const short8_t*)(Qg + (size_t)(n * 16 + lo) * 3072 + ks * 32 + hi * 8);
#pragma unroll
    for (int m = 0; m < 5; m++)
#pragma unroll
      for (int n = 0; n < 5; n++)
        sa[m][n] = __builtin_amdgcn_mfma_f32_16x16x32_bf16(ak[m], bq[n], sa[m][n], 0, 0, 0);
  }
  __syncthreads();

  // ---- softmax over keys per query column, then +bias, write P[q][key] bf16
  u16* p_lds = Kt;  // [80][104]; cols 80..95 zero (MFMA K-pad), 96..103 unused
  for (int i = lane; i < 80 * 16; i += 64) {
    int q = i >> 4, c = 80 + (i & 15);
    p_lds[q * 104 + c] = 0;
  }
  const float scale = 0.03125f;  // 1024^-0.5 (full emb scale, faithful)
#pragma unroll
  for (int n = 0; n < 5; n++) {
    float mx = -1e30f;
#pragma unroll
    for (int m = 0; m < 5; m++)
#pragma unroll
      for (int j = 0; j < 4; j++) {
        sa[m][n][j] *= scale;
        mx = fmaxf(mx, sa[m][n][j]);
      }
    mx = fmaxf(mx, __shfl_xor(mx, 16));
    mx = fmaxf(mx, __shfl_xor(mx, 32));
    float sm = 0.f;
#pragma unroll
    for (int m = 0; m < 5; m++)
#pragma unroll
      for (int j = 0; j < 4; j++) {
        float e = __expf(sa[m][n][j] - mx);
        sa[m][n][j] = e;
        sm += e;
      }
    sm += __shfl_xor(sm, 16);
    sm += __shfl_xor(sm, 32);
    float inv = 1.0f / sm;
    int q = n * 16 + lo;
#pragma unroll
    for (int m = 0; m < 5; m++)
#pragma unroll
      for (int j = 0; j < 4; j++) {
        int key = m * 16 + hi * 4 + j;
        float pv = sa[m][n][j] * inv + bias_l[q - key + 79];  // bias AFTER softmax
        p_lds[q * 104 + key] = f2bf(pv);
      }
  }
  __syncthreads();

  // ---- out[q][d] = P[q][key] * V[key][d]
#pragma unroll
  for (int half = 0; half < 2; half++) {
    f32x4 oa[5][4] = {};
#pragma unroll
    for (int ks = 0; ks < 3; ks++) {
      short8_t ap[5];
#pragma unroll
      for (int m = 0; m < 5; m++)
        ap[m] = *(const short8_t*)&p_lds[(m * 16 + lo) * 104 + ks * 32 + hi * 8];
      short8_t bv[4];
#pragma unroll
      for (int nd = 0; nd < 4; nd++) {
        int d = (half * 4 + nd) * 16 + lo;
        short8_t tt;
#pragma unroll
        for (int j = 0; j < 8; j++)
          tt[j] = (short)Vt[(ks * 32 + hi * 8 + j) * 128 + d];
        bv[nd] = tt;
      }
#pragma unroll
      for (int m = 0; m < 5; m++)
#pragma unroll
        for (int nd = 0; nd < 4; nd++)
          oa[m][nd] = __builtin_amdgcn_mfma_f32_16x16x32_bf16(ap[m], bv[nd], oa[m][nd], 0, 0, 0);
    }
#pragma unroll
    for (int m = 0; m < 5; m++)
#pragma unroll
      for (int nd = 0; nd < 4; nd++)
#pragma unroll
        for (int j = 0; j < 4; j++) {
          int q = m * 16 + hi * 4 + j;
          int d = (half * 4 + nd) * 16 + lo;
          attnout[((size_t)b * SEQ + q) * DIM + h * HDIM + d] = f2bf(oa[m][nd][j]);
        }
  }
}

// ---------------------------------------------------------------- fused LN chains
__device__ __forceinline__ void block_reduce2(float& a, float& b, float* sbuf) {
#pragma unroll
  for (int m = 1; m < 64; m <<= 1) {
    a += __shfl_xor(a, m);
    b += __shfl_xor(b, m);
  }
  int w = threadIdx.x >> 6;
  if ((threadIdx.x & 63) == 0) { sbuf[w * 2] = a; sbuf[w * 2 + 1] = b; }
  __syncthreads();
  a = sbuf[0] + sbuf[2] + sbuf[4] + sbuf[6];
  b = sbuf[1] + sbuf[3] + sbuf[5] + sbuf[7];
  __syncthreads();
}

// to_out LN on attnout (bf16), then x + out, then ln1 -> x1b (bf16)
__global__ __launch_bounds__(256) void fuse1_kernel(
    const u16* __restrict__ attnout, const float* __restrict__ x,
    const float* __restrict__ og, const float* __restrict__ ob,
    const float* __restrict__ g1, const float* __restrict__ b1,
    u16* __restrict__ x1b) {
  __shared__ float sbuf[8];
  const size_t base = (size_t)blockIdx.x * DIM;
  float a[4], r[4];
  float s0 = 0.f, s1 = 0.f;
#pragma unroll
  for (int i = 0; i < 4; i++) {
    int idx = threadIdx.x + i * 256;
    a[i] = bf2f(attnout[base + idx]);
    s0 += a[i];
    s1 += a[i] * a[i];
  }
  block_reduce2(s0, s1, sbuf);
  float mu = s0 * (1.f / DIM);
  float rstd = rsqrtf(s1 * (1.f / DIM) - mu * mu + 1e-5f);
  float t0 = 0.f, t1 = 0.f;
#pragma unroll
  for (int i = 0; i < 4; i++) {
    int idx = threadIdx.x + i * 256;
    float o = (a[i] - mu) * rstd * og[idx] + ob[idx];
    r[i] = x[base + idx] + o;
    t0 += r[i];
    t1 += r[i] * r[i];
  }
  block_reduce2(t0, t1, sbuf);
  float mu2 = t0 * (1.f / DIM);
  float rstd2 = rsqrtf(t1 * (1.f / DIM) - mu2 * mu2 + 1e-5f);
#pragma unroll
  for (int i = 0; i < 4; i++) {
    int idx = threadIdx.x + i * 256;
    x1b[base + idx] = f2bf((r[i] - mu2) * rstd2 * g1[idx] + b1[idx]);
  }
}

// out = ln2(x1 + ff)  (x1, ff bf16; out fp32)
__global__ __launch_bounds__(256) void fuse2_kernel(
    const u16* __restrict__ x1b, const u16* __restrict__ ff,
    const float* __restrict__ g2, const float* __restrict__ b2,
    float* __restrict__ out) {
  __shared__ float sbuf[8];
  const size_t base = (size_t)blockIdx.x * DIM;
  float r[4];
  float s0 = 0.f, s1 = 0.f;
#pragma unroll
  for (int i = 0; i < 4; i++) {
    int idx = threadIdx.x + i * 256;
    r[i] = bf2f(x1b[base + idx]) + bf2f(ff[base + idx]);
    s0 += r[i];
    s1 += r[i] * r[i];
  }
  block_reduce2(s0, s1, sbuf);
  float mu = s0 * (1.f / DIM);
  float rstd = rsqrtf(s1 * (1.f / DIM) - mu * mu + 1e-5f);
#pragma unroll
  for (int i = 0; i < 4; i++) {
    int idx = threadIdx.x + i * 256;
    out[base + idx] = (r[i] - mu) * rstd * g2[idx] + b2[idx];
  }
}

// ---------------------------------------------------------------- launch
extern "C" void kernel_launch(void* const* d_in, const int* in_sizes, int n_in,
                              void* d_out, int out_size, void* d_ws, size_t ws_size,
                              hipStream_t stream) {
  const float* x        = (const float*)d_in[0];
  const float* Wq       = (const float*)d_in[1];
  const float* Wk       = (const float*)d_in[2];
  const float* Wv       = (const float*)d_in[3];
  const float* bias_tab = (const float*)d_in[4];
  const float* og       = (const float*)d_in[5];
  const float* ob       = (const float*)d_in[6];
  const float* g1       = (const float*)d_in[7];
  const float* b1       = (const float*)d_in[8];
  const float* g2       = (const float*)d_in[9];
  const float* b2       = (const float*)d_in[10];
  const float* fc1w     = (const float*)d_in[11];
  const float* fc1b     = (const float*)d_in[12];
  const float* fc2w     = (const float*)d_in[13];
  const float* fc2b     = (const float*)d_in[14];

  // --- ws layout (fixed part = 106,954,752 B), C-region sized from ws_size ---
  char* ws = (char*)d_ws;
  u16* wqkvT = (u16*)(ws + 0);                 //  6,291,456  [3072][1024]
  u16* fc1T  = (u16*)(ws + 6291456ull);        //  8,388,608  [4096][1024]
  u16* fc2T  = (u16*)(ws + 14680064ull);       //  8,388,608  [1024][4096]
  u16* pbuf  = (u16*)(ws + 23068672ull);       // 41,943,040  attnout -> ff (bf16)
  u16* qbuf  = (u16*)(ws + 65011712ull);       // 41,943,040  xb -> x1b (bf16)
  char* cbuf = ws + 106954752ull;              // qkv chunks / h chunks
  size_t cavail = ws_size > 106954752ull ? ws_size - 106954752ull : 0;

  // chunk counts (deterministic in ws_size): qkv chunk = (BATCH/cb)*80*3072*2 B,
  // h chunk = (NTOK/cf)*4096*2 B. Both must fit cavail.
  int cb = 1;
  while (cb < 32 && (size_t)(BATCH / cb) * SEQ * 3072 * 2 > cavail) cb <<= 1;
  int cf = 1;
  while (cf < 16 && (size_t)(NTOK / cf) * HID * 2 > cavail) cf <<= 1;

  dim3 tb(32, 8);
  cast_bf16_kernel<<<2048, 256, 0, stream>>>(x, qbuf, NTOK * DIM / 4);
  transpose_cast_kernel<<<dim3(32, 32), tb, 0, stream>>>(Wq, wqkvT, 1024, 1024);
  transpose_cast_kernel<<<dim3(32, 32), tb, 0, stream>>>(Wk, wqkvT + 1024 * 1024, 1024, 1024);
  transpose_cast_kernel<<<dim3(32, 32), tb, 0, stream>>>(Wv, wqkvT + 2 * 1024 * 1024, 1024, 1024);
  transpose_cast_kernel<<<dim3(128, 32), tb, 0, stream>>>(fc1w, fc1T, 1024, 4096);
  transpose_cast_kernel<<<dim3(32, 128), tb, 0, stream>>>(fc2w, fc2T, 4096, 1024);

  // QKV projection + attention, chunked over batches
  {
    const int nb = BATCH / cb;                 // batches per chunk
    const int rows = nb * SEQ;                 // tokens per chunk (mult of 128 for cb<=32)
    u16* qkvc = (u16*)cbuf;
    for (int c = 0; c < cb; ++c) {
      const u16* xb_c = qbuf + (size_t)c * rows * DIM;
      gemm_bt<0><<<dim3(24, rows / 128), 256, 0, stream>>>(
          xb_c, wqkvT, nullptr, qkvc, rows, 3072, 1024);
      attn_kernel<<<nb * HEADS, 64, 0, stream>>>(
          qkvc, bias_tab, pbuf + (size_t)c * rows * DIM);
    }
  }

  fuse1_kernel<<<NTOK, 256, 0, stream>>>(pbuf, x, og, ob, g1, b1, qbuf);

  // FFN, chunked over token rows (pbuf now holds ff)
  {
    const int rows = NTOK / cf;                // mult of 128 for cf<=16
    u16* hc = (u16*)cbuf;
    for (int c = 0; c < cf; ++c) {
      gemm_bt<1><<<dim3(32, rows / 128), 256, 0, stream>>>(
          qbuf + (size_t)c * rows * DIM, fc1T, fc1b, hc, rows, HID, 1024);
      gemm_bt<2><<<dim3(8, rows / 128), 256, 0, stream>>>(
          hc, fc2T, fc2b, pbuf + (size_t)c * rows * DIM, rows, 1024, HID);
    }
  }

  fuse2_kernel<<<NTOK, 256, 0, stream>>>(qbuf, pbuf, g2, b2, (float*)d_out);
}

// Round 3
// 818.007 us; speedup vs baseline: 1.1885x; 1.1885x over previous
//
// Round 3: 256x256 deep-pipelined GEMM (BK=32, 4 LDS buffers, counted vmcnt,
// T2 XOR swizzle via pre-swizzled source, T5 setprio, T1 bijective XCD swizzle).
// Attention / LN / cast kernels unchanged from round 2 (passing).
#include <hip/hip_runtime.h>
#include <stdint.h>

#define BATCH 256
#define SEQ   80
#define DIM   1024
#define HEADS 8
#define HDIM  128
#define HID   4096
#define NTOK  (BATCH * SEQ)   // 20480

typedef unsigned short u16;
using short8_t = __attribute__((ext_vector_type(8))) short;   // 8 bf16 (4 VGPRs)
using f32x4    = __attribute__((ext_vector_type(4))) float;   // MFMA accumulator

__device__ __forceinline__ u16 f2bf(float f) {
  unsigned u = __float_as_uint(f);
  u += 0x7fffu + ((u >> 16) & 1u);   // RNE; inputs are finite
  return (u16)(u >> 16);
}
__device__ __forceinline__ float bf2f(u16 u) {
  return __uint_as_float(((unsigned)u) << 16);
}

__device__ __forceinline__ float gelu_exact(float v) {
  return 0.5f * v * (1.0f + erff(v * 0.70710678118654752f));
}

// async global->LDS, 16B per lane; lds dest = base + lane*16 (base wave-uniform)
#define GLD16(gp, lp)                                                   \
  __builtin_amdgcn_global_load_lds(                                     \
      (__attribute__((address_space(1))) void*)(void*)(gp),             \
      (__attribute__((address_space(3))) void*)(void*)(lp), 16, 0, 0)

// ---------------------------------------------------------------- casts
__global__ __launch_bounds__(256) void cast_bf16_kernel(
    const float* __restrict__ in, u16* __restrict__ out, int n4) {
  int i = blockIdx.x * 256 + threadIdx.x;
  int stride = gridDim.x * 256;
  for (; i < n4; i += stride) {
    float4 v = ((const float4*)in)[i];
    uint2 o;
    o.x = (unsigned)f2bf(v.x) | ((unsigned)f2bf(v.y) << 16);
    o.y = (unsigned)f2bf(v.z) | ((unsigned)f2bf(v.w) << 16);
    ((uint2*)out)[i] = o;
  }
}

// in: R x C fp32 row-major -> out: C x R bf16 row-major  (R,C multiples of 32)
__global__ __launch_bounds__(256) void transpose_cast_kernel(
    const float* __restrict__ in, u16* __restrict__ out, int R, int C) {
  __shared__ float tile[32][33];
  int c0 = blockIdx.x * 32, r0 = blockIdx.y * 32;
  for (int k = 0; k < 4; k++) {
    int i = threadIdx.y + k * 8;
    tile[i][threadIdx.x] = in[(size_t)(r0 + i) * C + c0 + threadIdx.x];
  }
  __syncthreads();
  for (int k = 0; k < 4; k++) {
    int i = threadIdx.y + k * 8;
    out[(size_t)(c0 + i) * R + r0 + threadIdx.x] = f2bf(tile[threadIdx.x][i]);
  }
}

// ---------------------------------------------------------------- GEMM 256x256 deep pipeline
// C[M,N] = A[M,K] * Bt[N,K]^T, bf16 out. BK=32, 4 LDS buffers, 8 waves (2Mx4N),
// per-wave 128x64 output (acc[8][4] of 16x16 frags). M,N mult of 256; K mult of 32, K>=128.
// Swizzle: physical k-block = logical ^ ((row>>1)&3); linear LDS dest (global_load_lds),
// inverse-swizzled global source, swizzled ds_read => 2 lanes/bank (conflict-free).
// vmcnt ledger: 4 loads/tile/thread, tile t+3 staged during iter t; vmcnt(8) at iter end
// => tiles <= t+1 landed. Tail: vmcnt 8 -> 4 -> 0.
// EPI: 0 = plain; 1 = +bias then exact GELU; 2 = +bias.
template <int EPI>
__global__ __launch_bounds__(512, 2) void gemm256(
    const u16* __restrict__ A, const u16* __restrict__ Bt,
    const float* __restrict__ bias, u16* __restrict__ outp,
    int M, int N, int K, int ntn) {
  __shared__ __align__(16) u16 lds[65536];   // 128 KiB: 4 bufs x (A 8K + B 8K u16)

  const int tid  = threadIdx.x;
  const int lane = tid & 63, wave = tid >> 6;
  const int wm = wave >> 2, wn = wave & 3;
  const int lo = lane & 15, hi = lane >> 4;

  // bijective XCD swizzle (m204 variant)
  const int nwg = gridDim.x;
  {
  }
  int q8 = nwg >> 3, r8 = nwg & 7;
  int xcd = blockIdx.x & 7, off = blockIdx.x >> 3;
  int swz = (xcd < r8 ? xcd * (q8 + 1) : r8 * (q8 + 1) + (xcd - r8) * q8) + off;
  const int bn = swz % ntn;
  const int bm = swz / ntn;
  const size_t arow0 = (size_t)bm * 256;
  const size_t bcol0 = (size_t)bn * 256;

  // staging: thread stages slots {tid, 512+tid} of each 16KB chunk.
  // slot s -> phys row s>>2, phys blk s&3; logical blk lb = (s&3) ^ ((s>>3)&3)
  // (same for both j since +512 slots = +128 rows, (128>>1)&3 == 0).
  const int prow = tid >> 2;
  const int lb = (tid & 3) ^ ((tid >> 3) & 3);
  const u16* srcA = A + (arow0 + prow) * K + lb * 8;
  const u16* srcB = Bt + (bcol0 + prow) * K + lb * 8;
  const size_t jstep = 128 * (size_t)K;   // j=1: +128 rows

  // LDS staging bases (wave-uniform), elements
  u16* ldsA0 = lds + wave * 512;
  u16* ldsA1 = lds + 4096 + wave * 512;
  u16* ldsB0 = lds + 8192 + wave * 512;
  u16* ldsB1 = lds + 12288 + wave * 512;

  // frag read offsets (elements within a 16K-elem buffer)
  const int blk = hi ^ ((lo >> 1) & 3);                  // swizzled k-block
  const int abase = (wm * 128 + lo) * 32 + blk * 8;
  const int bbase = 8192 + (wn * 64 + lo) * 32 + blk * 8;

  f32x4 acc[8][4] = {};
  const int NT = K >> 5;

  // prologue: stage tiles 0,1,2 (12 loads/thread); tile0 landed after vmcnt(8)
#pragma unroll
  for (int tt = 0; tt < 3; ++tt) {
    const u16* sa = srcA + (size_t)tt * 32;
    const u16* sb = srcB + (size_t)tt * 32;
    GLD16(sa, ldsA0 + tt * 16384);
    GLD16(sa + jstep, ldsA1 + tt * 16384);
    GLD16(sb, ldsB0 + tt * 16384);
    GLD16(sb + jstep, ldsB1 + tt * 16384);
  }
  asm volatile("s_waitcnt vmcnt(8)" ::: "memory");
  asm volatile("s_barrier" ::: "memory");

#define PHASES(T, DO_STAGE, VMASM)                                             \
  do {                                                                         \
    const int bufb = ((T) & 3) * 16384;                                        \
    short8_t a0[4], b0[4], a1[4];                                              \
    _Pragma("unroll") for (int m = 0; m < 4; ++m)                              \
        a0[m] = *(const short8_t*)&lds[bufb + abase + m * 512];                \
    _Pragma("unroll") for (int n = 0; n < 4; ++n)                              \
        b0[n] = *(const short8_t*)&lds[bufb + bbase + n * 512];                \
    if (DO_STAGE) {                                                            \
      const u16* sa = srcA + (size_t)((T) + 3) * 32;                           \
      GLD16(sa, ldsA0 + (((T) + 3) & 3) * 16384);                              \
      GLD16(sa + jstep, ldsA1 + (((T) + 3) & 3) * 16384);                      \
    }                                                                          \
    asm volatile("s_barrier" ::: "memory");                                    \
    __builtin_amdgcn_s_setprio(1);                                             \
    _Pragma("unroll") for (int m = 0; m < 4; ++m)                              \
        _Pragma("unroll") for (int n = 0; n < 4; ++n)                          \
            acc[m][n] = __builtin_amdgcn_mfma_f32_16x16x32_bf16(               \
                a0[m], b0[n], acc[m][n], 0, 0, 0);                             \
    __builtin_amdgcn_s_setprio(0);                                             \
    asm volatile("s_barrier" ::: "memory");                                    \
    _Pragma("unroll") for (int m = 0; m < 4; ++m)                              \
        a1[m] = *(const short8_t*)&lds[bufb + abase + (4 + m) * 512];          \
    if (DO_STAGE) {                                                            \
      const u16* sb = srcB + (size_t)((T) + 3) * 32;                           \
      GLD16(sb, ldsB0 + (((T) + 3) & 3) * 16384);                              \
      GLD16(sb + jstep, ldsB1 + (((T) + 3) & 3) * 16384);                      \
    }                                                                          \
    asm volatile("s_barrier" ::: "memory");                                    \
    __builtin_amdgcn_s_setprio(1);                                             \
    _Pragma("unroll") for (int m = 0; m < 4; ++m)                              \
        _Pragma("unroll") for (int n = 0; n < 4; ++n)                          \
            acc[4 + m][n] = __builtin_amdgcn_mfma_f32_16x16x32_bf16(           \
                a1[m], b0[n], acc[4 + m][n], 0, 0, 0);                         \
    __builtin_amdgcn_s_setprio(0);                                             \
    asm volatile(VMASM ::: "memory");                                          \
    asm volatile("s_barrier" ::: "memory");                                    \
  } while (0)

  for (int t = 0; t < NT - 3; ++t) PHASES(t, 1, "s_waitcnt vmcnt(8)");
  PHASES(NT - 3, 0, "s_waitcnt vmcnt(4)");
  PHASES(NT - 2, 0, "s_waitcnt vmcnt(0)");
  PHASES(NT - 1, 0, "");
#undef PHASES

  // epilogue
  const size_t crow0 = arow0 + wm * 128;
  const int ccol0 = (int)bcol0 + wn * 64;
#pragma unroll
  for (int n = 0; n < 4; ++n) {
    int col = ccol0 + n * 16 + lo;
    float bv = 0.f;
    if constexpr (EPI != 0) bv = bias[col];
#pragma unroll
    for (int m = 0; m < 8; ++m) {
#pragma unroll
      for (int j = 0; j < 4; ++j) {
        size_t row = crow0 + m * 16 + hi * 4 + j;
        float v = acc[m][n][j] + bv;
        if constexpr (EPI == 1) v = gelu_exact(v);
        outp[row * N + col] = f2bf(v);
      }
    }
  }
}

// ---------------------------------------------------------------- attention
// One wave per (local b, h). QKV chunk: [nb*80][3072] bf16 (Q|K|V, head h at h*128).
__global__ __launch_bounds__(64) void attn_kernel(
    const u16* __restrict__ QKV, const float* __restrict__ bias_table,
    u16* __restrict__ attnout) {
  __shared__ __align__(16) u16 Kt[80 * 128];   // [key][d]; reused as P [80][104]
  __shared__ __align__(16) u16 Vt[96 * 128];   // [key][d], rows 80..95 zeroed
  __shared__ float bias_l[159];

  const int bh = blockIdx.x;
  const int b = bh >> 3, h = bh & 7;
  const int lane = threadIdx.x, lo = lane & 15, hi = lane >> 4;
  const size_t tokbase = (size_t)b * SEQ * 3072;
  const u16* Qg = QKV + tokbase + h * HDIM;
  const u16* Kg = QKV + tokbase + 1024 + h * HDIM;
  const u16* Vg = QKV + tokbase + 2048 + h * HDIM;

#pragma unroll
  for (int i = 0; i < 20; i++) {
    int flat = i * 64 + lane;
    int row = flat >> 4;
    int col = (flat & 15) * 8;
    GLD16(Kg + (size_t)row * 3072 + col, &Kt[i * 512]);
    GLD16(Vg + (size_t)row * 3072 + col, &Vt[i * 512]);
  }
  for (int i = lane; i < 16 * 128; i += 64) Vt[80 * 128 + i] = 0;  // V pad rows
  for (int i = lane; i < 159; i += 64) bias_l[i] = bias_table[i * 8 + h];
  asm volatile("s_waitcnt vmcnt(0)" ::: "memory");
  __syncthreads();

  // ---- S^T[key][q] = K * Q^T
  f32x4 sa[5][5] = {};
#pragma unroll
  for (int ks = 0; ks < 4; ks++) {
    short8_t ak[5], bq[5];
#pragma unroll
    for (int m = 0; m < 5; m++)
      ak[m] = *(const short8_t*)&Kt[(m * 16 + lo) * 128 + ks * 32 + hi * 8];
#pragma unroll
    for (int n = 0; n < 5; n++)
      bq[n] = *(const short8_t*)(Qg + (size_t)(n * 16 + lo) * 3072 + ks * 32 + hi * 8);
#pragma unroll
    for (int m = 0; m < 5; m++)
#pragma unroll
      for (int n = 0; n < 5; n++)
        sa[m][n] = __builtin_amdgcn_mfma_f32_16x16x32_bf16(ak[m], bq[n], sa[m][n], 0, 0, 0);
  }
  __syncthreads();

  // ---- softmax over keys per query column, then +bias, write P[q][key] bf16
  u16* p_lds = Kt;  // [80][104]; cols 80..95 zero (MFMA K-pad), 96..103 unused
  for (int i = lane; i < 80 * 16; i += 64) {
    int q = i >> 4, c = 80 + (i & 15);
    p_lds[q * 104 + c] = 0;
  }
  const float scale = 0.03125f;  // 1024^-0.5 (full emb scale, faithful)
#pragma unroll
  for (int n = 0; n < 5; n++) {
    float mx = -1e30f;
#pragma unroll
    for (int m = 0; m < 5; m++)
#pragma unroll
      for (int j = 0; j < 4; j++) {
        sa[m][n][j] *= scale;
        mx = fmaxf(mx, sa[m][n][j]);
      }
    mx = fmaxf(mx, __shfl_xor(mx, 16));
    mx = fmaxf(mx, __shfl_xor(mx, 32));
    float sm = 0.f;
#pragma unroll
    for (int m = 0; m < 5; m++)
#pragma unroll
      for (int j = 0; j < 4; j++) {
        float e = __expf(sa[m][n][j] - mx);
        sa[m][n][j] = e;
        sm += e;
      }
    sm += __shfl_xor(sm, 16);
    sm += __shfl_xor(sm, 32);
    float inv = 1.0f / sm;
    int q = n * 16 + lo;
#pragma unroll
    for (int m = 0; m < 5; m++)
#pragma unroll
      for (int j = 0; j < 4; j++) {
        int key = m * 16 + hi * 4 + j;
        float pv = sa[m][n][j] * inv + bias_l[q - key + 79];  // bias AFTER softmax
        p_lds[q * 104 + key] = f2bf(pv);
      }
  }
  __syncthreads();

  // ---- out[q][d] = P[q][key] * V[key][d]
#pragma unroll
  for (int half = 0; half < 2; half++) {
    f32x4 oa[5][4] = {};
#pragma unroll
    for (int ks = 0; ks < 3; ks++) {
      short8_t ap[5];
#pragma unroll
      for (int m = 0; m < 5; m++)
        ap[m] = *(const short8_t*)&p_lds[(m * 16 + lo) * 104 + ks * 32 + hi * 8];
      short8_t bv[4];
#pragma unroll
      for (int nd = 0; nd < 4; nd++) {
        int d = (half * 4 + nd) * 16 + lo;
        short8_t tt;
#pragma unroll
        for (int j = 0; j < 8; j++)
          tt[j] = (short)Vt[(ks * 32 + hi * 8 + j) * 128 + d];
        bv[nd] = tt;
      }
#pragma unroll
      for (int m = 0; m < 5; m++)
#pragma unroll
        for (int nd = 0; nd < 4; nd++)
          oa[m][nd] = __builtin_amdgcn_mfma_f32_16x16x32_bf16(ap[m], bv[nd], oa[m][nd], 0, 0, 0);
    }
#pragma unroll
    for (int m = 0; m < 5; m++)
#pragma unroll
      for (int nd = 0; nd < 4; nd++)
#pragma unroll
        for (int j = 0; j < 4; j++) {
          int q = m * 16 + hi * 4 + j;
          int d = (half * 4 + nd) * 16 + lo;
          attnout[((size_t)b * SEQ + q) * DIM + h * HDIM + d] = f2bf(oa[m][nd][j]);
        }
  }
}

// ---------------------------------------------------------------- fused LN chains
__device__ __forceinline__ void block_reduce2(float& a, float& b, float* sbuf) {
#pragma unroll
  for (int m = 1; m < 64; m <<= 1) {
    a += __shfl_xor(a, m);
    b += __shfl_xor(b, m);
  }
  int w = threadIdx.x >> 6;
  if ((threadIdx.x & 63) == 0) { sbuf[w * 2] = a; sbuf[w * 2 + 1] = b; }
  __syncthreads();
  a = sbuf[0] + sbuf[2] + sbuf[4] + sbuf[6];
  b = sbuf[1] + sbuf[3] + sbuf[5] + sbuf[7];
  __syncthreads();
}

// to_out LN on attnout (bf16), then x + out, then ln1 -> x1b (bf16)
__global__ __launch_bounds__(256) void fuse1_kernel(
    const u16* __restrict__ attnout, const float* __restrict__ x,
    const float* __restrict__ og, const float* __restrict__ ob,
    const float* __restrict__ g1, const float* __restrict__ b1,
    u16* __restrict__ x1b) {
  __shared__ float sbuf[8];
  const size_t base = (size_t)blockIdx.x * DIM;
  float a[4], r[4];
  float s0 = 0.f, s1 = 0.f;
#pragma unroll
  for (int i = 0; i < 4; i++) {
    int idx = threadIdx.x + i * 256;
    a[i] = bf2f(attnout[base + idx]);
    s0 += a[i];
    s1 += a[i] * a[i];
  }
  block_reduce2(s0, s1, sbuf);
  float mu = s0 * (1.f / DIM);
  float rstd = rsqrtf(s1 * (1.f / DIM) - mu * mu + 1e-5f);
  float t0 = 0.f, t1 = 0.f;
#pragma unroll
  for (int i = 0; i < 4; i++) {
    int idx = threadIdx.x + i * 256;
    float o = (a[i] - mu) * rstd * og[idx] + ob[idx];
    r[i] = x[base + idx] + o;
    t0 += r[i];
    t1 += r[i] * r[i];
  }
  block_reduce2(t0, t1, sbuf);
  float mu2 = t0 * (1.f / DIM);
  float rstd2 = rsqrtf(t1 * (1.f / DIM) - mu2 * mu2 + 1e-5f);
#pragma unroll
  for (int i = 0; i < 4; i++) {
    int idx = threadIdx.x + i * 256;
    x1b[base + idx] = f2bf((r[i] - mu2) * rstd2 * g1[idx] + b1[idx]);
  }
}

// out = ln2(x1 + ff)  (x1, ff bf16; out fp32)
__global__ __launch_bounds__(256) void fuse2_kernel(
    const u16* __restrict__ x1b, const u16* __restrict__ ff,
    const float* __restrict__ g2, const float* __restrict__ b2,
    float* __restrict__ out) {
  __shared__ float sbuf[8];
  const size_t base = (size_t)blockIdx.x * DIM;
  float r[4];
  float s0 = 0.f, s1 = 0.f;
#pragma unroll
  for (int i = 0; i < 4; i++) {
    int idx = threadIdx.x + i * 256;
    r[i] = bf2f(x1b[base + idx]) + bf2f(ff[base + idx]);
    s0 += r[i];
    s1 += r[i] * r[i];
  }
  block_reduce2(s0, s1, sbuf);
  float mu = s0 * (1.f / DIM);
  float rstd = rsqrtf(s1 * (1.f / DIM) - mu * mu + 1e-5f);
#pragma unroll
  for (int i = 0; i < 4; i++) {
    int idx = threadIdx.x + i * 256;
    out[base + idx] = (r[i] - mu) * rstd * g2[idx] + b2[idx];
  }
}

// ---------------------------------------------------------------- launch
extern "C" void kernel_launch(void* const* d_in, const int* in_sizes, int n_in,
                              void* d_out, int out_size, void* d_ws, size_t ws_size,
                              hipStream_t stream) {
  const float* x        = (const float*)d_in[0];
  const float* Wq       = (const float*)d_in[1];
  const float* Wk       = (const float*)d_in[2];
  const float* Wv       = (const float*)d_in[3];
  const float* bias_tab = (const float*)d_in[4];
  const float* og       = (const float*)d_in[5];
  const float* ob       = (const float*)d_in[6];
  const float* g1       = (const float*)d_in[7];
  const float* b1       = (const float*)d_in[8];
  const float* g2       = (const float*)d_in[9];
  const float* b2       = (const float*)d_in[10];
  const float* fc1w     = (const float*)d_in[11];
  const float* fc1b     = (const float*)d_in[12];
  const float* fc2w     = (const float*)d_in[13];
  const float* fc2b     = (const float*)d_in[14];

  // --- ws layout (fixed part = 106,954,752 B), C-region sized from ws_size ---
  char* ws = (char*)d_ws;
  u16* wqkvT = (u16*)(ws + 0);                 //  6,291,456  [3072][1024]
  u16* fc1T  = (u16*)(ws + 6291456ull);        //  8,388,608  [4096][1024]
  u16* fc2T  = (u16*)(ws + 14680064ull);       //  8,388,608  [1024][4096]
  u16* pbuf  = (u16*)(ws + 23068672ull);       // 41,943,040  attnout -> ff (bf16)
  u16* qbuf  = (u16*)(ws + 65011712ull);       // 41,943,040  xb -> x1b (bf16)
  char* cbuf = ws + 106954752ull;              // qkv chunks / h chunks
  size_t cavail = ws_size > 106954752ull ? ws_size - 106954752ull : 0;

  // chunk counts (deterministic in ws_size); rows stay multiples of 256.
  int cb = 1;
  while (cb < 16 && (size_t)(BATCH / cb) * SEQ * 3072 * 2 > cavail) cb <<= 1;
  int cf = 1;
  while (cf < 16 && (size_t)(NTOK / cf) * HID * 2 > cavail) cf <<= 1;

  dim3 tb(32, 8);
  cast_bf16_kernel<<<2048, 256, 0, stream>>>(x, qbuf, NTOK * DIM / 4);
  transpose_cast_kernel<<<dim3(32, 32), tb, 0, stream>>>(Wq, wqkvT, 1024, 1024);
  transpose_cast_kernel<<<dim3(32, 32), tb, 0, stream>>>(Wk, wqkvT + 1024 * 1024, 1024, 1024);
  transpose_cast_kernel<<<dim3(32, 32), tb, 0, stream>>>(Wv, wqkvT + 2 * 1024 * 1024, 1024, 1024);
  transpose_cast_kernel<<<dim3(128, 32), tb, 0, stream>>>(fc1w, fc1T, 1024, 4096);
  transpose_cast_kernel<<<dim3(32, 128), tb, 0, stream>>>(fc2w, fc2T, 4096, 1024);

  // QKV projection + attention, chunked over batches
  {
    const int nb = BATCH / cb;                 // batches per chunk
    const int rows = nb * SEQ;                 // multiple of 256 for cb<=16
    u16* qkvc = (u16*)cbuf;
    const int nwg = (rows / 256) * (3072 / 256);
    for (int c = 0; c < cb; ++c) {
      const u16* xb_c = qbuf + (size_t)c * rows * DIM;
      gemm256<0><<<nwg, 512, 0, stream>>>(xb_c, wqkvT, nullptr, qkvc,
                                          rows, 3072, 1024, 3072 / 256);
      attn_kernel<<<nb * HEADS, 64, 0, stream>>>(
          qkvc, bias_tab, pbuf + (size_t)c * rows * DIM);
    }
  }

  fuse1_kernel<<<NTOK, 256, 0, stream>>>(pbuf, x, og, ob, g1, b1, qbuf);

  // FFN, chunked over token rows (pbuf now holds ff)
  {
    const int rows = NTOK / cf;                // multiple of 256 for cf<=16
    u16* hc = (u16*)cbuf;
    const int nwg1 = (rows / 256) * (HID / 256);
    const int nwg2 = (rows / 256) * (DIM / 256);
    for (int c = 0; c < cf; ++c) {
      gemm256<1><<<nwg1, 512, 0, stream>>>(qbuf + (size_t)c * rows * DIM, fc1T,
                                           fc1b, hc, rows, HID, 1024, HID / 256);
      gemm256<2><<<nwg2, 512, 0, stream>>>(hc, fc2T, fc2b,
                                           pbuf + (size_t)c * rows * DIM,
                                           rows, 1024, HID, DIM / 256);
    }
  }

  fuse2_kernel<<<NTOK, 256, 0, stream>>>(qbuf, pbuf, g2, b2, (float*)d_out);
}